// Round 1
// baseline (529.262 us; speedup 1.0000x reference)
//
#include <hip/hip_runtime.h>
#include <hip/hip_bf16.h>

typedef __bf16 bf16_t;
typedef __bf16 bf16x8 __attribute__((ext_vector_type(8)));
typedef __bf16 bf16x4 __attribute__((ext_vector_type(4)));
typedef float f32x4 __attribute__((ext_vector_type(4)));

#define QS   256.0f
#define QINV 0.00390625f

__device__ __forceinline__ void async_copy16(const bf16_t* g, bf16_t* l) {
  __builtin_amdgcn_global_load_lds(
      (__attribute__((address_space(1))) void*)g,
      (__attribute__((address_space(3))) void*)l,
      16, 0, 0);
}

// C = quantize-epilogue(A @ Bt^T + bias)
// A:  [M][K] bf16 row-major
// Bt: [N][K] bf16 row-major (i.e. B transposed)
// GELU=true: out = f2f(pwl_gelu(f2f(c))) stored as OutT (bf16 for h)
// GELU=false: out = f2f(c) stored as float
template <bool GELU, typename OutT>
__global__ __launch_bounds__(256, 2)
void gemm_tile(const bf16_t* __restrict__ A, const bf16_t* __restrict__ Bt,
               const float* __restrict__ bias, OutT* __restrict__ C,
               int M, int N, int K) {
  __shared__ __attribute__((aligned(16))) bf16_t As[128 * 64];
  __shared__ __attribute__((aligned(16))) bf16_t Bs[128 * 64];
  __shared__ float Yt[33];

  const int tid = threadIdx.x;
  const int lane = tid & 63;
  const int wv = tid >> 6;
  const int wy = wv >> 1;   // wave row (0/1) -> 64 rows
  const int wx = wv & 1;    // wave col (0/1) -> 64 cols
  const int l15 = lane & 15;
  const int lq = lane >> 4; // quad 0..3

  if (GELU && tid < 33) {
    float xv = -4.0f + 0.25f * (float)tid;
    Yt[tid] = 0.5f * xv * (1.0f + erff(xv * 0.70710678f));
  }

  const int mBase = blockIdx.y * 128;
  const int nBase = blockIdx.x * 128;

  const bf16_t* aTile = A + (size_t)mBase * K;
  const bf16_t* bTile = Bt + (size_t)nBase * K;

  f32x4 acc[4][4];
#pragma unroll
  for (int i = 0; i < 4; ++i)
#pragma unroll
    for (int j = 0; j < 4; ++j)
      acc[i][j] = (f32x4){0.f, 0.f, 0.f, 0.f};

  const int srow = tid >> 3;       // 0..31 (row within 32-row pass)
  const int scb = (tid & 7) * 8;   // col element offset (8 bf16 = 16B per lane)

  for (int k0 = 0; k0 < K; k0 += 64) {
    // ---- stage A,B tiles (128 x 64 bf16 each) via async global->LDS, 16B/lane
#pragma unroll
    for (int p = 0; p < 4; ++p) {
      const int row = p * 32 + srow;
      const size_t go = (size_t)row * K + k0 + scb;
      const int lo = (p * 256 + wv * 64) * 8;  // wave-uniform segment base (elements)
      async_copy16(aTile + go, As + lo);
      async_copy16(bTile + go, Bs + lo);
    }
    __syncthreads();  // drains vmcnt: tiles resident

    // ---- compute: 2 k-substeps of 32, 16 MFMA each per wave
#pragma unroll
    for (int ks = 0; ks < 2; ++ks) {
      const int kofs = ks * 32 + lq * 8;
      bf16x8 af[4], bfr[4];
#pragma unroll
      for (int i = 0; i < 4; ++i) {
        af[i]  = *(const bf16x8*)(As + (wy * 64 + i * 16 + l15) * 64 + kofs);
        bfr[i] = *(const bf16x8*)(Bs + (wx * 64 + i * 16 + l15) * 64 + kofs);
      }
#pragma unroll
      for (int i = 0; i < 4; ++i)
#pragma unroll
        for (int j = 0; j < 4; ++j)
          acc[i][j] = __builtin_amdgcn_mfma_f32_16x16x32_bf16(af[i], bfr[j], acc[i][j], 0, 0, 0);
    }
    __syncthreads();  // all waves done reading before next stage
  }

  // ---- epilogue: bias + quantize (+ PWL GELU)
  float bj[4];
#pragma unroll
  for (int j = 0; j < 4; ++j)
    bj[j] = bias[nBase + wx * 64 + j * 16 + l15];

#pragma unroll
  for (int i = 0; i < 4; ++i) {
    const int rb = mBase + wy * 64 + i * 16 + lq * 4;
#pragma unroll
    for (int j = 0; j < 4; ++j) {
      const int cn = nBase + wx * 64 + j * 16 + l15;
#pragma unroll
      for (int r = 0; r < 4; ++r) {
        float c = acc[i][j][r] + bj[j];
        float v;
        if (GELU) {
          float xq = rintf(c * QS) * QINV;           // float2fix (Positional_0)
          if (xq > 4.0f) {
            v = xq;
          } else if (xq < -4.0f) {
            v = 0.0f;
          } else {
            float t = (xq + 4.0f) * 4.0f;            // exact: /0.25
            int ii = (int)t;
            ii = ii > 31 ? 31 : ii;
            float f = t - (float)ii;
            float y0 = Yt[ii];
            v = fmaf(f, Yt[ii + 1] - y0, y0);
          }
          v = rintf(v * QS) * QINV;                  // quantize out (+Positional_1 idempotent)
        } else {
          v = rintf(c * QS) * QINV;                  // Positional_2
        }
        C[(size_t)(rb + r) * N + cn] = (OutT)v;
      }
    }
  }
}

__global__ void cvt_bf16_kernel(const float* __restrict__ in, bf16_t* __restrict__ out, int n4) {
  int idx = blockIdx.x * blockDim.x + threadIdx.x;
  if (idx < n4) {
    const float4 v = ((const float4*)in)[idx];
    bf16x4 o;
    o[0] = (bf16_t)v.x; o[1] = (bf16_t)v.y; o[2] = (bf16_t)v.z; o[3] = (bf16_t)v.w;
    ((bf16x4*)out)[idx] = o;
  }
}

// in: [R][C] f32 row-major -> out: [C][R] bf16 row-major
__global__ void transpose_cvt_kernel(const float* __restrict__ in, bf16_t* __restrict__ out,
                                     int R, int C) {
  __shared__ float t[32][33];
  const int c0 = blockIdx.x * 32;
  const int r0 = blockIdx.y * 32;
  const int tx = threadIdx.x;
  const int ty = threadIdx.y;  // 0..7
#pragma unroll
  for (int dy = 0; dy < 32; dy += 8)
    t[ty + dy][tx] = in[(size_t)(r0 + ty + dy) * C + c0 + tx];
  __syncthreads();
#pragma unroll
  for (int dy = 0; dy < 32; dy += 8)
    out[(size_t)(c0 + ty + dy) * R + r0 + tx] = (bf16_t)t[tx][ty + dy];
}

extern "C" void kernel_launch(void* const* d_in, const int* in_sizes, int n_in,
                              void* d_out, int out_size, void* d_ws, size_t ws_size,
                              hipStream_t stream) {
  const float* x  = (const float*)d_in[0];   // [32,512,1024] = [16384][1024]
  const float* w1 = (const float*)d_in[1];   // [1024][4096]
  const float* b1 = (const float*)d_in[2];   // [4096]
  const float* w2 = (const float*)d_in[3];   // [4096][1024]
  const float* b2 = (const float*)d_in[4];   // [1024]
  float* out = (float*)d_out;                // [16384][1024]

  const int M = 16384, D = 1024, F = 4096;

  char* ws = (char*)d_ws;
  size_t off = 0;
  bf16_t* xb  = (bf16_t*)(ws + off); off += (size_t)M * D * 2;  // 33.5 MB
  bf16_t* w1t = (bf16_t*)(ws + off); off += (size_t)D * F * 2;  //  8.4 MB
  bf16_t* w2t = (bf16_t*)(ws + off); off += (size_t)F * D * 2;  //  8.4 MB
  bf16_t* h   = (bf16_t*)(ws + off);                            // 134.2 MB

  cvt_bf16_kernel<<<(M * D / 4 + 255) / 256, 256, 0, stream>>>(x, xb, M * D / 4);
  transpose_cvt_kernel<<<dim3(F / 32, D / 32), dim3(32, 8), 0, stream>>>(w1, w1t, D, F);
  transpose_cvt_kernel<<<dim3(D / 32, F / 32), dim3(32, 8), 0, stream>>>(w2, w2t, F, D);

  // GEMM1 + quantize + PWL-GELU + quantize -> h (bf16)
  gemm_tile<true, bf16_t><<<dim3(F / 128, M / 128), 256, 0, stream>>>(xb, w1t, b1, h, M, F, D);
  // GEMM2 + quantize -> out (f32)
  gemm_tile<false, float><<<dim3(D / 128, M / 128), 256, 0, stream>>>(h, w2t, b2, out, M, D, F);
}

// Round 2
// 453.456 us; speedup vs baseline: 1.1672x; 1.1672x over previous
//
#include <hip/hip_runtime.h>
#include <hip/hip_bf16.h>

typedef __bf16 bf16_t;
typedef __bf16 bf16x8 __attribute__((ext_vector_type(8)));
typedef __bf16 bf16x4 __attribute__((ext_vector_type(4)));
typedef float f32x4 __attribute__((ext_vector_type(4)));

#define QS   256.0f
#define QINV 0.00390625f

__device__ __forceinline__ void async_copy16(const bf16_t* g, bf16_t* l) {
  __builtin_amdgcn_global_load_lds(
      (__attribute__((address_space(1))) void*)g,
      (__attribute__((address_space(3))) void*)l,
      16, 0, 0);
}

// C = quantize-epilogue(A @ Bt^T + bias)
// A:  [M][K] bf16 row-major
// Bt: [N][K] bf16 row-major (i.e. B transposed)
// LDS tiles use an XOR-swizzled chunk layout: the 16B chunk that logically
// belongs at column-chunk c of row r is stored at physical chunk c ^ (r & 7).
// Implemented on the staging side by permuting which global chunk each lane
// fetches (global_load_lds pins LDS slot = base + lane*16). This spreads the
// 16 rows of a quad's ds_read_b128 across all 32 banks (2-way alias = free)
// instead of a 16-way conflict on one 4-bank group.
template <bool GELU, typename OutT>
__global__ __launch_bounds__(256, 4)
void gemm_tile(const bf16_t* __restrict__ A, const bf16_t* __restrict__ Bt,
               const float* __restrict__ bias, OutT* __restrict__ C,
               int M, int N, int K) {
  __shared__ __attribute__((aligned(16))) bf16_t As[128 * 64];
  __shared__ __attribute__((aligned(16))) bf16_t Bs[128 * 64];
  __shared__ float Yt[33];

  const int tid = threadIdx.x;
  const int lane = tid & 63;
  const int wv = tid >> 6;
  const int wy = wv >> 1;   // wave row (0/1) -> 64 rows
  const int wx = wv & 1;    // wave col (0/1) -> 64 cols
  const int l15 = lane & 15;
  const int lq = lane >> 4; // quad 0..3

  if (GELU && tid < 33) {
    float xv = -4.0f + 0.25f * (float)tid;
    Yt[tid] = 0.5f * xv * (1.0f + erff(xv * 0.70710678f));
  }

  const int mBase = blockIdx.y * 128;
  const int nBase = blockIdx.x * 128;

  const bf16_t* aTile = A + (size_t)mBase * K;
  const bf16_t* bTile = Bt + (size_t)nBase * K;

  f32x4 acc[4][4];
#pragma unroll
  for (int i = 0; i < 4; ++i)
#pragma unroll
    for (int j = 0; j < 4; ++j)
      acc[i][j] = (f32x4){0.f, 0.f, 0.f, 0.f};

  const int srow = tid >> 3;                              // 0..31 (row within 32-row pass)
  const int scb = (((tid & 7) ^ ((tid >> 3) & 7)) * 8);   // swizzled global chunk for this lane

  // read-side swizzle base: physical chunk = (ks*4 + lq) ^ (l15 & 7)
  const int swz_r = l15 & 7;

  for (int k0 = 0; k0 < K; k0 += 64) {
    // ---- stage A,B tiles (128 x 64 bf16 each) via async global->LDS, 16B/lane
#pragma unroll
    for (int p = 0; p < 4; ++p) {
      const int row = p * 32 + srow;
      const size_t go = (size_t)row * K + k0 + scb;
      const int lo = (p * 256 + wv * 64) * 8;  // wave-uniform segment base (elements)
      async_copy16(aTile + go, As + lo);
      async_copy16(bTile + go, Bs + lo);
    }
    __syncthreads();  // drains vmcnt: tiles resident

    // ---- compute: 2 k-substeps of 32, 16 MFMA each per wave
#pragma unroll
    for (int ks = 0; ks < 2; ++ks) {
      const int swzA = ((ks * 4 + lq) ^ swz_r) * 8;  // physical chunk offset (elements)
      bf16x8 af[4], bfr[4];
#pragma unroll
      for (int i = 0; i < 4; ++i) {
        af[i]  = *(const bf16x8*)(As + (wy * 64 + i * 16 + l15) * 64 + swzA);
        bfr[i] = *(const bf16x8*)(Bs + (wx * 64 + i * 16 + l15) * 64 + swzA);
      }
#pragma unroll
      for (int i = 0; i < 4; ++i)
#pragma unroll
        for (int j = 0; j < 4; ++j)
          acc[i][j] = __builtin_amdgcn_mfma_f32_16x16x32_bf16(af[i], bfr[j], acc[i][j], 0, 0, 0);
    }
    __syncthreads();  // all waves done reading before next stage
  }

  // ---- epilogue: bias + quantize (+ PWL GELU)
  float bj[4];
#pragma unroll
  for (int j = 0; j < 4; ++j)
    bj[j] = bias[nBase + wx * 64 + j * 16 + l15];

#pragma unroll
  for (int i = 0; i < 4; ++i) {
    const int rb = mBase + wy * 64 + i * 16 + lq * 4;
#pragma unroll
    for (int j = 0; j < 4; ++j) {
      const int cn = nBase + wx * 64 + j * 16 + l15;
#pragma unroll
      for (int r = 0; r < 4; ++r) {
        float c = acc[i][j][r] + bj[j];
        float v;
        if (GELU) {
          float xq = rintf(c * QS) * QINV;           // float2fix (Positional_0)
          if (xq > 4.0f) {
            v = xq;
          } else if (xq < -4.0f) {
            v = 0.0f;
          } else {
            float t = (xq + 4.0f) * 4.0f;            // exact: /0.25
            int ii = (int)t;
            ii = ii > 31 ? 31 : ii;
            float f = t - (float)ii;
            float y0 = Yt[ii];
            v = fmaf(f, Yt[ii + 1] - y0, y0);
          }
          v = rintf(v * QS) * QINV;                  // quantize out (+Positional_1 idempotent)
        } else {
          v = rintf(c * QS) * QINV;                  // Positional_2
        }
        C[(size_t)(rb + r) * N + cn] = (OutT)v;
      }
    }
  }
}

__global__ void cvt_bf16_kernel(const float* __restrict__ in, bf16_t* __restrict__ out, int n4) {
  int idx = blockIdx.x * blockDim.x + threadIdx.x;
  if (idx < n4) {
    const float4 v = ((const float4*)in)[idx];
    bf16x4 o;
    o[0] = (bf16_t)v.x; o[1] = (bf16_t)v.y; o[2] = (bf16_t)v.z; o[3] = (bf16_t)v.w;
    ((bf16x4*)out)[idx] = o;
  }
}

// in: [R][C] f32 row-major -> out: [C][R] bf16 row-major
__global__ void transpose_cvt_kernel(const float* __restrict__ in, bf16_t* __restrict__ out,
                                     int R, int C) {
  __shared__ float t[32][33];
  const int c0 = blockIdx.x * 32;
  const int r0 = blockIdx.y * 32;
  const int tx = threadIdx.x;
  const int ty = threadIdx.y;  // 0..7
#pragma unroll
  for (int dy = 0; dy < 32; dy += 8)
    t[ty + dy][tx] = in[(size_t)(r0 + ty + dy) * C + c0 + tx];
  __syncthreads();
#pragma unroll
  for (int dy = 0; dy < 32; dy += 8)
    out[(size_t)(c0 + ty + dy) * R + r0 + tx] = (bf16_t)t[tx][ty + dy];
}

extern "C" void kernel_launch(void* const* d_in, const int* in_sizes, int n_in,
                              void* d_out, int out_size, void* d_ws, size_t ws_size,
                              hipStream_t stream) {
  const float* x  = (const float*)d_in[0];   // [32,512,1024] = [16384][1024]
  const float* w1 = (const float*)d_in[1];   // [1024][4096]
  const float* b1 = (const float*)d_in[2];   // [4096]
  const float* w2 = (const float*)d_in[3];   // [4096][1024]
  const float* b2 = (const float*)d_in[4];   // [1024]
  float* out = (float*)d_out;                // [16384][1024]

  const int M = 16384, D = 1024, F = 4096;

  char* ws = (char*)d_ws;
  size_t off = 0;
  bf16_t* xb  = (bf16_t*)(ws + off); off += (size_t)M * D * 2;  // 33.5 MB
  bf16_t* w1t = (bf16_t*)(ws + off); off += (size_t)D * F * 2;  //  8.4 MB
  bf16_t* w2t = (bf16_t*)(ws + off); off += (size_t)F * D * 2;  //  8.4 MB
  bf16_t* h   = (bf16_t*)(ws + off);                            // 134.2 MB

  cvt_bf16_kernel<<<(M * D / 4 + 255) / 256, 256, 0, stream>>>(x, xb, M * D / 4);
  transpose_cvt_kernel<<<dim3(F / 32, D / 32), dim3(32, 8), 0, stream>>>(w1, w1t, D, F);
  transpose_cvt_kernel<<<dim3(D / 32, F / 32), dim3(32, 8), 0, stream>>>(w2, w2t, F, D);

  // GEMM1 + quantize + PWL-GELU + quantize -> h (bf16)
  gemm_tile<true, bf16_t><<<dim3(F / 128, M / 128), 256, 0, stream>>>(xb, w1t, b1, h, M, F, D);
  // GEMM2 + quantize -> out (f32)
  gemm_tile<false, float><<<dim3(D / 128, M / 128), 256, 0, stream>>>(h, w2t, b2, out, M, D, F);
}